// Round 12
// baseline (1540.625 us; speedup 1.0000x reference)
//
#include <hip/hip_runtime.h>
#include <hip/hip_fp16.h>

typedef unsigned int uint;
typedef unsigned short ushort;
typedef unsigned long long ull;

#define B 16
#define N 4096
#define S 1024          // NPOINT
#define K 32            // NSAMPLE
#define NPOS (B*S*K)    // 524288
#define NPAIR (NPOS/2)  // 262144
#define NBS (B*S)       // 16384

__device__ inline float h2f(ushort b) {
    __half h; *(ushort*)&h = b; return __half2float(h);
}
__device__ inline ushort f2h(float v) {
    __half h = __float2half(v); return *(ushort*)&h;
}

// ---- fused FPS (blocks 0..15) + feature transpose (blocks 16..527) ----
// Round-6 structure verbatim (measured best: 680 us).
__global__ __launch_bounds__(512) void fps_tr_kernel(const float* __restrict__ xyz,
                                                     float* __restrict__ new_xyz,
                                                     const float* __restrict__ feat,
                                                     float* __restrict__ featT) {
    __shared__ float4 lc[N];      // 64 KB
    __shared__ ull slot[3];
    const int lt = threadIdx.x;   // 0..511

    if (blockIdx.x >= 16) {
        // ---------- transpose path ----------
        float* tile = (float*)lc;             // 2 * 64*65 floats = 33 KB
        const int tb = blockIdx.x - 16;       // 0..511
        const int b  = tb >> 5;               // batch
        const int nb = (tb & 31) << 7;        // 128-col chunk
        const int h  = lt >> 8;               // half: 0/1
        const int tt = lt & 255;
        const int tn = tt & 63;
        const int r  = tt >> 6;               // 0..3
        float* mytile = tile + h * (64 * 65);
        const int n0 = nb + (h << 6);
        for (int c = r; c < 64; c += 4)
            mytile[c * 65 + tn] = feat[((size_t)b * 64 + c) * N + n0 + tn];
        __syncthreads();
        for (int n = r; n < 64; n += 4)
            featT[((size_t)b * N + n0 + n) * 64 + tn] = mytile[tn * 65 + n];
        return;
    }

    // ---------- FPS path ----------
    const int b = blockIdx.x;
    const float* xb = xyz + (size_t)b * N * 3;
    float px[8], py[8], pz[8], dist[8];
    uint njc[8];
    #pragma unroll
    for (int p = 0; p < 8; ++p) {
        const int j = lt + (p << 9);
        float x = xb[j*3+0], y = xb[j*3+1], z = xb[j*3+2];
        lc[j] = make_float4(x, y, z, 0.f);
        px[p] = x; py[p] = y; pz[p] = z;
        dist[p] = 1e10f;
        njc[p] = ~(uint)j;
    }
    if (lt < 3) slot[lt] = 0ull;
    __syncthreads();

    float4 c0 = lc[0];
    float cx = c0.x, cy = c0.y, cz = c0.z;
    float* outb = new_xyz + (size_t)b * S * 3;

    int cur = 0;
    for (int s = 0; s < S; ++s) {
        if (lt == 0) { outb[s*3+0] = cx; outb[s*3+1] = cy; outb[s*3+2] = cz; }

        ull best = 0ull;
        #pragma unroll
        for (int p = 0; p < 8; ++p) {
            float dx = px[p] - cx, dy = py[p] - cy, dz = pz[p] - cz;
            float d  = __fadd_rn(__fadd_rn(__fmul_rn(dx,dx), __fmul_rn(dy,dy)), __fmul_rn(dz,dz));
            float nd = fminf(dist[p], d);
            dist[p] = nd;
            ull pk = ((ull)__float_as_uint(nd) << 32) | (ull)njc[p];
            if (pk > best) best = pk;
        }
        // butterfly within 32-lane groups via ds_swizzle (xor 1,2,4,8,16)
        {
            uint blo = (uint)best, bhi = (uint)(best >> 32);
            #define FPS_LVL(MASK) { \
                uint olo = (uint)__builtin_amdgcn_ds_swizzle((int)blo, MASK); \
                uint ohi = (uint)__builtin_amdgcn_ds_swizzle((int)bhi, MASK); \
                ull o = ((ull)ohi << 32) | (ull)olo; \
                if (o > best) { best = o; bhi = ohi; blo = olo; } }
            FPS_LVL(0x041F)   // xor 1
            FPS_LVL(0x081F)   // xor 2
            FPS_LVL(0x101F)   // xor 4
            FPS_LVL(0x201F)   // xor 8
            FPS_LVL(0x401F)   // xor 16
            #undef FPS_LVL
        }
        if ((lt & 31) == 0) atomicMax(&slot[cur], best);
        int nxt = cur + 1; if (nxt == 3) nxt = 0;
        if (lt == 0) slot[nxt] = 0ull;   // slot last read 2 barriers ago (safe)
        __syncthreads();
        ull pk = slot[cur];
        int last = (int)(~(uint)pk);     // lo32 = ~j exactly
        float4 c4 = lc[last];
        cx = c4.x; cy = c4.y; cz = c4.z;
        cur = nxt;
    }
}

// ---------------- ball query: one wave per center ----------------
__global__ __launch_bounds__(256) void ballq_kernel(const float* __restrict__ xyz,
                                                    const float* __restrict__ new_xyz,
                                                    int* __restrict__ idx) {
    const int wid  = (blockIdx.x * 256 + threadIdx.x) >> 6;   // center id
    const int lane = threadIdx.x & 63;
    const int b = wid >> 10;
    const float* xb = xyz + (size_t)b * N * 3;
    const float cx = new_xyz[(size_t)wid*3+0];
    const float cy = new_xyz[(size_t)wid*3+1];
    const float cz = new_xyz[(size_t)wid*3+2];
    int* ob = idx + (size_t)wid * K;

    const float R2 = 0.04f;  // float32(0.2*0.2) per JAX weak-type demotion
    int total = 0;
    int first = 0;
    bool gotfirst = false;
    for (int c0 = 0; c0 < N; c0 += 64) {
        const int j = c0 + lane;
        float dx = cx - xb[j*3+0];
        float dy = cy - xb[j*3+1];
        float dz = cz - xb[j*3+2];
        float d2 = __fadd_rn(__fadd_rn(__fmul_rn(dx,dx), __fmul_rn(dy,dy)), __fmul_rn(dz,dz));
        bool inr = d2 < R2;
        unsigned long long bal = __ballot(inr);
        if (bal) {
            if (!gotfirst) { first = c0 + __builtin_ctzll(bal); gotfirst = true; }
            int rank = __popcll(bal & ((1ull << lane) - 1ull));
            int pos = total + rank;
            if (inr && pos < K) ob[pos] = j;
            total += __popcll(bal);
            if (total >= K) break;
        }
    }
    for (int p2 = total + lane; p2 < K; p2 += 64) ob[p2] = first;
}

// ---------------- conv0: LDS-tiled GEMM + fused stats0 ----------------
__global__ __launch_bounds__(256) void conv0_kernel(const float* __restrict__ xyz,
                                                    const float* __restrict__ new_xyz,
                                                    const float* __restrict__ featT,
                                                    const int* __restrict__ idx,
                                                    const float* __restrict__ w0,
                                                    const float* __restrict__ b0,
                                                    ushort* __restrict__ x0,
                                                    float* __restrict__ st0) {
    __shared__ float xt[68][128];   // 34.8 KB
    __shared__ float wt[68][64];    // 17.4 KB
    __shared__ float lds_s[64], lds_q[64];
    const int t  = threadIdx.x;
    const int p0 = blockIdx.x * 128;

    for (int i = t; i < 68*64; i += 256) {
        const int k = i >> 6, o = i & 63;
        wt[k][o] = (k < 67) ? w0[(size_t)o*67 + k] : 0.f;
    }
    if (t < 64) { lds_s[t] = 0.f; lds_q[t] = 0.f; }
    if (t < 128) {
        const int p  = p0 + t;
        const int bs = p >> 5;
        const int b  = p >> 15;
        const int j  = idx[p];
        const float* xp = xyz + ((size_t)b*N + (size_t)j)*3;
        xt[0][t] = xp[0] - new_xyz[(size_t)bs*3+0];
        xt[1][t] = xp[1] - new_xyz[(size_t)bs*3+1];
        xt[2][t] = xp[2] - new_xyz[(size_t)bs*3+2];
    } else {
        xt[67][t-128] = 0.f;
    }
    #pragma unroll
    for (int r = 0; r < 8; ++r) {
        const int i = t + (r << 8);
        const int q = i >> 7;           // 0..15
        const int p = i & 127;
        const int gp = p0 + p;
        const int b  = gp >> 15;
        const int j  = idx[gp];
        const float4 v = *(const float4*)(featT + ((((size_t)b*N + j) << 6) + (q << 2)));
        xt[3 + 4*q + 0][p] = v.x;
        xt[3 + 4*q + 1][p] = v.y;
        xt[3 + 4*q + 2][p] = v.z;
        xt[3 + 4*q + 3][p] = v.w;
    }
    __syncthreads();

    const int po = t >> 3;   // 0..31 -> positions po*4 .. po*4+3
    const int og = t & 7;    // outputs og*8 .. og*8+7
    float a[4][8];
    #pragma unroll
    for (int i = 0; i < 8; ++i) {
        const float bv = b0[og*8 + i];
        a[0][i] = bv; a[1][i] = bv; a[2][i] = bv; a[3][i] = bv;
    }
    #pragma unroll 2
    for (int k = 0; k < 68; ++k) {
        const float4 xv = *(const float4*)&xt[k][po*4];
        float w[8];
        *(float4*)&w[0] = *(const float4*)&wt[k][og*8];
        *(float4*)&w[4] = *(const float4*)&wt[k][og*8+4];
        #pragma unroll
        for (int i = 0; i < 8; ++i) {
            a[0][i] = fmaf(w[i], xv.x, a[0][i]);
            a[1][i] = fmaf(w[i], xv.y, a[1][i]);
            a[2][i] = fmaf(w[i], xv.z, a[2][i]);
            a[3][i] = fmaf(w[i], xv.w, a[3][i]);
        }
    }
    // store fp16 + per-thread stats on fp16-rounded values
    float s8[8], q8[8];
    #pragma unroll
    for (int i = 0; i < 8; ++i) {
        const int o = og*8 + i;
        ushort u0 = f2h(a[0][i]), u1 = f2h(a[1][i]), u2 = f2h(a[2][i]), u3 = f2h(a[3][i]);
        uint2 wd;
        wd.x = (uint)u0 | ((uint)u1 << 16);
        wd.y = (uint)u2 | ((uint)u3 << 16);
        *(uint2*)(x0 + (size_t)o*NPOS + p0 + po*4) = wd;
        float v0 = h2f(u0), v1 = h2f(u1), v2 = h2f(u2), v3 = h2f(u3);
        s8[i] = (v0 + v1) + (v2 + v3);
        q8[i] = (v0*v0 + v1*v1) + (v2*v2 + v3*v3);
    }
    // reduce over po-lanes (bits 3,4,5 of lane) within wave
    #pragma unroll
    for (int i = 0; i < 8; ++i) {
        s8[i] += __shfl_xor(s8[i], 8);  q8[i] += __shfl_xor(q8[i], 8);
        s8[i] += __shfl_xor(s8[i], 16); q8[i] += __shfl_xor(q8[i], 16);
        s8[i] += __shfl_xor(s8[i], 32); q8[i] += __shfl_xor(q8[i], 32);
    }
    if ((t & 63) < 8) {   // leader lane per og (lane == og)
        #pragma unroll
        for (int i = 0; i < 8; ++i) {
            atomicAdd(&lds_s[og*8 + i], s8[i]);
            atomicAdd(&lds_q[og*8 + i], q8[i]);
        }
    }
    __syncthreads();
    if (t < 64) {
        atomicAdd(&st0[t],      lds_s[t]);
        atomicAdd(&st0[64 + t], lds_q[t]);
    }
}

// ---------------- conv_mid1: BN0(relu)->64x64, writes x1, fused stats1 ----------------
__global__ __launch_bounds__(256) void conv_mid1_kernel(const ushort* __restrict__ xin,
                                                        const float* __restrict__ st0,
                                                        const float* __restrict__ g,
                                                        const float* __restrict__ be,
                                                        const float* __restrict__ w,
                                                        const float* __restrict__ bias,
                                                        ushort* __restrict__ xout,
                                                        float* __restrict__ st1) {
    __shared__ float sc_[64], sh_[64], lds_s[64], lds_q[64];
    const int t = threadIdx.x;
    if (t < 64) {
        const float invn = 1.0f / (float)NPOS;
        float mean = st0[t] * invn;
        float var  = st0[64+t] * invn - mean*mean;
        float inv  = 1.0f / sqrtf(var + 1e-5f);
        float scv  = g[t] * inv;
        sc_[t] = scv;
        sh_[t] = fmaf(-mean, scv, be[t]);
        lds_s[t] = 0.f; lds_q[t] = 0.f;
    }
    __syncthreads();

    const int pp = blockIdx.x * 256 + t;   // pair index < NPAIR
    float a0[64], a1[64];
    #pragma unroll
    for (int o = 0; o < 64; ++o) { a0[o] = bias[o]; a1[o] = a0[o]; }
    const uint* xr = (const uint*)xin;
    #pragma unroll 4
    for (int c = 0; c < 64; ++c) {
        uint u = xr[(size_t)c * NPAIR + pp];
        float v0 = h2f((ushort)(u & 0xffff));
        float v1 = h2f((ushort)(u >> 16));
        float sc = sc_[c], sh = sh_[c];
        v0 = fmaxf(0.0f, fmaf(v0, sc, sh));
        v1 = fmaxf(0.0f, fmaf(v1, sc, sh));
        const float* wr = w + c;
        #pragma unroll
        for (int o = 0; o < 64; ++o) {
            float wv = wr[o*64];
            a0[o] = fmaf(wv, v0, a0[o]);
            a1[o] = fmaf(wv, v1, a1[o]);
        }
    }
    uint* orow = (uint*)xout;
    #pragma unroll
    for (int ch = 0; ch < 4; ++ch) {
        float s16[16], q16[16];
        #pragma unroll
        for (int i = 0; i < 16; ++i) {
            const int o = ch*16 + i;
            ushort u0 = f2h(a0[o]), u1 = f2h(a1[o]);
            orow[(size_t)o * NPAIR + pp] = (uint)u0 | ((uint)u1 << 16);
            float v0 = h2f(u0), v1 = h2f(u1);
            s16[i] = v0 + v1;
            q16[i] = v0*v0 + v1*v1;
        }
        #pragma unroll
        for (int i = 0; i < 16; ++i) {
            s16[i] += __shfl_xor(s16[i], 1);  q16[i] += __shfl_xor(q16[i], 1);
            s16[i] += __shfl_xor(s16[i], 2);  q16[i] += __shfl_xor(q16[i], 2);
            s16[i] += __shfl_xor(s16[i], 4);  q16[i] += __shfl_xor(q16[i], 4);
            s16[i] += __shfl_xor(s16[i], 8);  q16[i] += __shfl_xor(q16[i], 8);
            s16[i] += __shfl_xor(s16[i], 16); q16[i] += __shfl_xor(q16[i], 16);
            s16[i] += __shfl_xor(s16[i], 32); q16[i] += __shfl_xor(q16[i], 32);
        }
        if ((t & 63) == 0) {
            #pragma unroll
            for (int i = 0; i < 16; ++i) {
                atomicAdd(&lds_s[ch*16 + i], s16[i]);
                atomicAdd(&lds_q[ch*16 + i], q16[i]);
            }
        }
    }
    __syncthreads();
    if (t < 64) {
        atomicAdd(&st1[t],      lds_s[t]);
        atomicAdd(&st1[64 + t], lds_q[t]);
    }
}

// ---------------- conv_mid2: BN1(relu)->64ch half, fused maxpool + per-bs sums ----------------
// No x2 materialization. Per 16-thread group (one bs): fp16-rounded raw max /
// sum / sumsq over its 32 k-positions, written coalesced to [bs][64] buffers.
__global__ __launch_bounds__(256) void conv_mid2_kernel(const ushort* __restrict__ xin,
                                                        const float* __restrict__ st1,
                                                        const float* __restrict__ g,
                                                        const float* __restrict__ be,
                                                        const float* __restrict__ w,
                                                        const float* __restrict__ bias,
                                                        int wbase,
                                                        float* __restrict__ maxraw,
                                                        float* __restrict__ sums,
                                                        float* __restrict__ sumsq) {
    __shared__ float sc_[64], sh_[64];
    const int t = threadIdx.x;
    if (t < 64) {
        const float invn = 1.0f / (float)NPOS;
        float mean = st1[t] * invn;
        float var  = st1[64+t] * invn - mean*mean;
        float inv  = 1.0f / sqrtf(var + 1e-5f);
        float scv  = g[t] * inv;
        sc_[t] = scv;
        sh_[t] = fmaf(-mean, scv, be[t]);
    }
    __syncthreads();

    const int pp = blockIdx.x * 256 + t;
    float a0[64], a1[64];
    #pragma unroll
    for (int o = 0; o < 64; ++o) { a0[o] = bias[wbase + o]; a1[o] = a0[o]; }
    const uint* xr = (const uint*)xin;
    #pragma unroll 4
    for (int c = 0; c < 64; ++c) {
        uint u = xr[(size_t)c * NPAIR + pp];
        float v0 = h2f((ushort)(u & 0xffff));
        float v1 = h2f((ushort)(u >> 16));
        float sc = sc_[c], sh = sh_[c];
        v0 = fmaxf(0.0f, fmaf(v0, sc, sh));
        v1 = fmaxf(0.0f, fmaf(v1, sc, sh));
        const float* wr = w + (size_t)wbase * 64 + c;
        #pragma unroll
        for (int o = 0; o < 64; ++o) {
            float wv = wr[o*64];
            a0[o] = fmaf(wv, v0, a0[o]);
            a1[o] = fmaf(wv, v1, a1[o]);
        }
    }
    const int bs = pp >> 4;                 // 16 pairs (32 k) per bs
    const bool leader = (t & 15) == 0;
    #pragma unroll
    for (int ch = 0; ch < 4; ++ch) {
        float m16[16], s16[16], q16[16];
        #pragma unroll
        for (int i = 0; i < 16; ++i) {
            const int o = ch*16 + i;
            ushort u0 = f2h(a0[o]), u1 = f2h(a1[o]);
            float v0 = h2f(u0), v1 = h2f(u1);
            m16[i] = fmaxf(v0, v1);
            s16[i] = v0 + v1;
            q16[i] = v0*v0 + v1*v1;
        }
        #pragma unroll
        for (int i = 0; i < 16; ++i) {
            m16[i] = fmaxf(m16[i], __shfl_xor(m16[i], 1));
            s16[i] += __shfl_xor(s16[i], 1);  q16[i] += __shfl_xor(q16[i], 1);
            m16[i] = fmaxf(m16[i], __shfl_xor(m16[i], 2));
            s16[i] += __shfl_xor(s16[i], 2);  q16[i] += __shfl_xor(q16[i], 2);
            m16[i] = fmaxf(m16[i], __shfl_xor(m16[i], 4));
            s16[i] += __shfl_xor(s16[i], 4);  q16[i] += __shfl_xor(q16[i], 4);
            m16[i] = fmaxf(m16[i], __shfl_xor(m16[i], 8));
            s16[i] += __shfl_xor(s16[i], 8);  q16[i] += __shfl_xor(q16[i], 8);
        }
        if (leader) {
            #pragma unroll
            for (int k = 0; k < 4; ++k) {
                const int o = ch*16 + k*4;
                *(float4*)&maxraw[(size_t)bs*64 + o] =
                    make_float4(m16[k*4], m16[k*4+1], m16[k*4+2], m16[k*4+3]);
                *(float4*)&sums[(size_t)bs*64 + o] =
                    make_float4(s16[k*4], s16[k*4+1], s16[k*4+2], s16[k*4+3]);
                *(float4*)&sumsq[(size_t)bs*64 + o] =
                    make_float4(q16[k*4], q16[k*4+1], q16[k*4+2], q16[k*4+3]);
            }
        }
    }
}

// ---------------- stats reduce for layer 2 -> scale/shift ----------------
__global__ __launch_bounds__(256) void statsred_kernel(const float* __restrict__ sums,
                                                       const float* __restrict__ sumsq,
                                                       const float* __restrict__ g2,
                                                       const float* __restrict__ be2,
                                                       float* __restrict__ st) {
    const int c = blockIdx.x;               // 0..127
    const int h = c >> 6, cl = c & 63;
    const float* sp = sums  + ((size_t)h * NBS) * 64 + cl;
    const float* qp = sumsq + ((size_t)h * NBS) * 64 + cl;
    const int t = threadIdx.x;
    float s = 0.f, q = 0.f;
    for (int k = 0; k < 64; ++k) {
        const size_t bs = (size_t)t + ((size_t)k << 8);
        s += sp[bs * 64];
        q += qp[bs * 64];
    }
    #pragma unroll
    for (int off = 32; off; off >>= 1) { s += __shfl_xor(s, off); q += __shfl_xor(q, off); }
    __shared__ float ls[4], lq[4];
    const int w = t >> 6;
    if ((t & 63) == 0) { ls[w] = s; lq[w] = q; }
    __syncthreads();
    if (t == 0) {
        float Sv = ls[0]+ls[1]+ls[2]+ls[3];
        float Qv = lq[0]+lq[1]+lq[2]+lq[3];
        const float invn = 1.0f / (float)NPOS;
        float mean = Sv * invn;
        float var  = Qv * invn - mean*mean;
        float inv  = 1.0f / sqrtf(var + 1e-5f);
        float scv  = g2[c] * inv;
        st[256 + c] = scv;
        st[384 + c] = fmaf(-mean, scv, be2[c]);
    }
}

// ---------------- final: BN2+relu on raw maxes, transpose to (b,c,s) ----------------
__global__ __launch_bounds__(256) void finalout_kernel(const float* __restrict__ maxraw,
                                                       const float* __restrict__ st,
                                                       float* __restrict__ out) {
    __shared__ float tile[128][65];
    const int t = threadIdx.x;
    const int bs0 = blockIdx.x << 6;        // 64 bs per block
    const int b = bs0 >> 10, s0 = bs0 & 1023;
    #pragma unroll
    for (int it = 0; it < 32; ++it) {
        const int idxv = (it << 8) + t;
        const int c = idxv & 127, bsl = idxv >> 7;
        const float v = maxraw[((size_t)(c >> 6) * NBS + bs0 + bsl) * 64 + (c & 63)];
        tile[c][bsl] = fmaxf(fmaf(v, st[256 + c], st[384 + c]), 0.f);
    }
    __syncthreads();
    const int c = t >> 1, half = (t & 1) << 5;
    float* op = out + (((size_t)b * 128 + c) << 10) + s0 + half;
    #pragma unroll
    for (int i = 0; i < 8; ++i) {
        const int bl = half + (i << 2);
        *(float4*)(op + (i << 2)) =
            make_float4(tile[c][bl], tile[c][bl+1], tile[c][bl+2], tile[c][bl+3]);
    }
}

extern "C" void kernel_launch(void* const* d_in, const int* in_sizes, int n_in,
                              void* d_out, int out_size, void* d_ws, size_t ws_size,
                              hipStream_t stream) {
    const float* xyz      = (const float*)d_in[0];
    const float* features = (const float*)d_in[1];
    const float* w0 = (const float*)d_in[2];
    const float* b0 = (const float*)d_in[3];
    const float* g0 = (const float*)d_in[4];
    const float* be0= (const float*)d_in[5];
    const float* w1 = (const float*)d_in[6];
    const float* b1 = (const float*)d_in[7];
    const float* g1 = (const float*)d_in[8];
    const float* be1= (const float*)d_in[9];
    const float* w2 = (const float*)d_in[10];
    const float* b2 = (const float*)d_in[11];
    const float* g2 = (const float*)d_in[12];
    const float* be2= (const float*)d_in[13];

    float* out      = (float*)d_out;
    float* new_xyz  = out;              // (B,S,3)
    float* new_feat = out + (size_t)B*S*3;

    // Workspace (peak ~146 MB):
    //   [0,2MB)   idx | [2,18MB) featT | [18MB,+2KB) stats
    //   [A=18MB+64KB, +64MB) x0 ; reused after conv_mid1 as maxraw/sums/sumsq
    //   [A+64MB, +64MB) x1
    char* ws = (char*)d_ws;
    int*    idx   = (int*)ws;
    float*  featT = (float*)(ws + (2u<<20));
    float*  stats = (float*)(ws + (18u<<20));        // st0:0-127 st1:128-255 st2:256-511
    ushort* x0    = (ushort*)(ws + (18u<<20) + (1u<<16));
    ushort* x1    = x0 + (size_t)64 * NPOS;
    float*  mraw  = (float*)x0;                      // [2][NBS][64]  8 MB
    float*  sums  = mraw + (size_t)2 * NBS * 64;     // 8 MB
    float*  sumsq = sums + (size_t)2 * NBS * 64;     // 8 MB
    float* st0 = stats, *st1 = stats + 128;

    hipMemsetAsync(stats, 0, 256 * sizeof(float), stream);

    fps_tr_kernel<<<16 + 512, 512, 0, stream>>>(xyz, new_xyz, features, featT);
    ballq_kernel<<<(B*S)/4, 256, 0, stream>>>(xyz, new_xyz, idx);
    conv0_kernel<<<NPOS/128, 256, 0, stream>>>(xyz, new_xyz, featT, idx, w0, b0, x0, st0);
    conv_mid1_kernel<<<NPAIR/256, 256, 0, stream>>>(x0, st0, g0, be0, w1, b1, x1, st1);
    // layer 2 halves: x0 region is dead now; maxraw/sums/sumsq alias it
    conv_mid2_kernel<<<NPAIR/256, 256, 0, stream>>>(x1, st1, g1, be1, w2, b2, 0,
                                                    mraw, sums, sumsq);
    conv_mid2_kernel<<<NPAIR/256, 256, 0, stream>>>(x1, st1, g1, be1, w2, b2, 64,
                                                    mraw + (size_t)NBS*64,
                                                    sums + (size_t)NBS*64,
                                                    sumsq + (size_t)NBS*64);
    statsred_kernel<<<128, 256, 0, stream>>>(sums, sumsq, g2, be2, stats);
    finalout_kernel<<<NBS/64, 256, 0, stream>>>(mraw, stats, new_feat);
}